// Round 7
// baseline (720.316 us; speedup 1.0000x reference)
//
#include <hip/hip_runtime.h>

#define NCH 64      // channels
#define KOFF 27     // kernel offsets
#define EPSV 1e-5f

typedef __attribute__((ext_vector_type(8))) short  bf16x8;
typedef __attribute__((ext_vector_type(4))) float  f32x4;
typedef __attribute__((ext_vector_type(8))) unsigned short u16x8;

__device__ __forceinline__ unsigned short f2bf(float x) {
    unsigned int u = __float_as_uint(x);
    u += 0x7fffu + ((u >> 16) & 1u);       // round-to-nearest-even
    return (unsigned short)(u >> 16);
}

// ---------------------------------------------------------------------------
// Manual grid barrier (graph-capture-safe; no cooperative API).
// SAFE because all blocks are structurally co-resident: LDS 30.2KB -> 5
// blocks/CU, launch_bounds(256,4) -> VGPR<=128 -> 4 blocks/CU; capacity
// 4*256 = 1024 >= grid 782, independent of dispatch order (G16).
// ---------------------------------------------------------------------------
__device__ __forceinline__ void grid_arrive_wait(unsigned* bar, unsigned nblk)
{
    __syncthreads();
    if (threadIdx.x == 0) {
        __threadfence();                       // release prior stats atomics
        __hip_atomic_fetch_add(bar, 1u, __ATOMIC_ACQ_REL,
                               __HIP_MEMORY_SCOPE_AGENT);
        while (__hip_atomic_load(bar, __ATOMIC_ACQUIRE,
                                 __HIP_MEMORY_SCOPE_AGENT) < nblk)
            __builtin_amdgcn_s_sleep(16);
    }
    __syncthreads();
}

// ---------------------------------------------------------------------------
// Fused prep: zero stats+barriers | W1->Wt1 | W2->Wt2 | feats->bf16
// Wt[(((k*2+s)*4+ct)*64+lane)*8 + j] = W[k][s*32+(lane>>4)*8+j][ct*16+(lane&15)]
// ---------------------------------------------------------------------------
__global__ __launch_bounds__(256)
void prep_kernel(const float* __restrict__ feats,
                 const float* __restrict__ W1, const float* __restrict__ W2,
                 unsigned short* __restrict__ fbf,
                 unsigned short* __restrict__ wt1, unsigned short* __restrict__ wt2,
                 float* __restrict__ stat, int total8)
{
    const int b = blockIdx.x;
    if (b == 0) {
        stat[threadIdx.x] = 0.f;           // 256 floats: stats1+stats2
        if (threadIdx.x < 2)               // 2 barrier counters
            ((unsigned*)(stat + 256))[threadIdx.x] = 0u;
        return;
    }
    if (b <= 108) {
        const float* W = (b <= 54) ? W1 : W2;
        unsigned short* Wt = (b <= 54) ? wt1 : wt2;
        const int t = (b <= 54 ? b - 1 : b - 55) * 256 + threadIdx.x; // 0..13823
        const int l  = t & 63;
        const int ct = (t >> 6) & 3;
        const int s  = (t >> 8) & 1;
        const int k  = t >> 9;
        const int d     = ct * 16 + (l & 15);
        const int cbase = s * 32 + (l >> 4) * 8;
        u16x8 o;
#pragma unroll
        for (int j = 0; j < 8; ++j)
            o[j] = f2bf(W[(size_t)k * 4096 + (size_t)(cbase + j) * 64 + d]);
        reinterpret_cast<u16x8*>(Wt)[t] = o;
        return;
    }
    const int idx = (b - 109) * 256 + threadIdx.x;
    if (idx >= total8) return;
    const float4* xp = reinterpret_cast<const float4*>(feats) + (size_t)idx * 2;
    const float4 a = xp[0], c = xp[1];
    u16x8 o;
    o[0] = f2bf(a.x); o[1] = f2bf(a.y); o[2] = f2bf(a.z); o[3] = f2bf(a.w);
    o[4] = f2bf(c.x); o[5] = f2bf(c.y); o[6] = f2bf(c.z); o[7] = f2bf(c.w);
    reinterpret_cast<u16x8*>(fbf)[idx] = o;
}

// ---------------------------------------------------------------------------
// Fused conv+BN (r5 conv structure: 4 waves/block, 128 voxels, weights via
// LDS in 2-offset chunks = 16KB, total LDS 30.2KB). After the conv:
// block-reduced stats -> device-scope atomicAdd -> manual grid barrier ->
// BN applied to the block's OWN register tile -> single store.
// phase 0: store bf16 relu(bn1(acc));  phase 1: fp32 relu(bn2(acc)+feats).
// The conv output never round-trips through HBM before BN.
// ---------------------------------------------------------------------------
__global__ __launch_bounds__(256, 4)
void conv_fused(const unsigned short* __restrict__ fin,
                const int* __restrict__ nbr,
                const unsigned short* __restrict__ Wt,
                const float* __restrict__ bias,
                float* __restrict__ stats,          // 128 floats: sum, sumsq
                unsigned* __restrict__ bar,         // barrier counter
                const float* __restrict__ gmm, const float* __restrict__ bet,
                float invN, void* __restrict__ dst,
                const float* __restrict__ resid, int N, int phase)
{
    __shared__ int            s_idx[128 * KOFF];   // 13824 B
    __shared__ unsigned short s_w[2 * 4096];       // 16384 B (2 weight tiles)

    const int lane = threadIdx.x & 63;
    const int wv   = threadIdx.x >> 6;        // 0..3
    const int n0   = blockIdx.x * 128;
    const int m    = lane & 15;
    const int quad = lane >> 4;

    {   // stage 3456 ints cooperatively, pre-scaled to byte offsets
        const int rem  = N - n0;
        const int maxi = (rem < 128 ? rem : 128) * KOFF;
        const int* nb  = nbr + (size_t)n0 * KOFF;
        for (int p = threadIdx.x; p < 128 * KOFF; p += 256)
            s_idx[p] = ((p < maxi) ? nb[p] : 0) * (NCH * 2);
    }
    __syncthreads();

    f32x4 acc[2][4];
#pragma unroll
    for (int mt = 0; mt < 2; ++mt)
#pragma unroll
        for (int ct = 0; ct < 4; ++ct) acc[mt][ct] = (f32x4){0.f, 0.f, 0.f, 0.f};

    bf16x8 A[2][2][2];   // [parity][m-tile][s] : double-buffered
    bf16x8 B[2][4];      // [s][ct] from LDS
    const char* finB = (const char*)fin;
    const int lv0 = wv * 32;

#define LOADA(kk, par)                                                       \
    {                                                                        \
        _Pragma("unroll")                                                    \
        for (int mt = 0; mt < 2; ++mt) {                                     \
            const int ofs = s_idx[(lv0 + mt * 16 + m) * KOFF + (kk)];        \
            const char* fp = finB + ofs + quad * 16;                         \
            A[par][mt][0] = *reinterpret_cast<const bf16x8*>(fp);            \
            A[par][mt][1] = *reinterpret_cast<const bf16x8*>(fp + 64);       \
        }                                                                    \
    }

#define LOADB_LDS(sl)                                                        \
    {                                                                        \
        const unsigned short* wp = s_w + (sl) * 4096 + lane * 8;             \
        _Pragma("unroll")                                                    \
        for (int s = 0; s < 2; ++s)                                          \
            _Pragma("unroll")                                                \
            for (int ct = 0; ct < 4; ++ct)                                   \
                B[s][ct] =                                                   \
                    *reinterpret_cast<const bf16x8*>(wp + (s * 4 + ct) * 512);\
    }

#define DOMFMA(par)                                                          \
    {                                                                        \
        _Pragma("unroll")                                                    \
        for (int mt = 0; mt < 2; ++mt)                                       \
            _Pragma("unroll")                                                \
            for (int s = 0; s < 2; ++s)                                      \
                _Pragma("unroll")                                            \
                for (int ct = 0; ct < 4; ++ct)                               \
                    acc[mt][ct] = __builtin_amdgcn_mfma_f32_16x16x32_bf16(   \
                        A[par][mt][s], B[s][ct], acc[mt][ct], 0, 0, 0);      \
    }

    LOADA(0, 0);                               // first A prefetch in flight

    // 13 chunks of 2 offsets (k = kb, kb+1); parity position-static.
#pragma unroll 1
    for (int kb = 0; kb < KOFF - 1; kb += 2) {
        {   // stage 2 weight tiles: 16KB coalesced by 256 threads
            const u16x8* gw = reinterpret_cast<const u16x8*>(Wt) + (size_t)kb * 512;
            u16x8* lw = reinterpret_cast<u16x8*>(s_w);
#pragma unroll
            for (int i = 0; i < 4; ++i)        // 4*256 = 1024 = 2*512 units
                lw[threadIdx.x + i * 256] = gw[threadIdx.x + i * 256];
        }
        __syncthreads();                       // s_w ready

        LOADA(kb + 1, 1);
        LOADB_LDS(0);
        __builtin_amdgcn_sched_barrier(0);
        DOMFMA(0);

        LOADA(kb + 2, 0);                      // kb+2 <= 26 always valid
        LOADB_LDS(1);
        __builtin_amdgcn_sched_barrier(0);
        DOMFMA(1);

        __syncthreads();                       // done with s_w
    }
    {   // tail: k = 26 (A already prefetched, parity 0)
        const u16x8* gw = reinterpret_cast<const u16x8*>(Wt) + (size_t)26 * 512;
        u16x8* lw = reinterpret_cast<u16x8*>(s_w);
#pragma unroll
        for (int i = 0; i < 2; ++i)
            lw[threadIdx.x + i * 256] = gw[threadIdx.x + i * 256];
        __syncthreads();
        LOADB_LDS(0);
        __builtin_amdgcn_sched_barrier(0);
        DOMFMA(0);
        __syncthreads();
    }
#undef LOADA
#undef LOADB_LDS
#undef DOMFMA

    // ---- bias into acc, per-wave stats -> LDS -> per-block atomicAdd ----
    float* s_red = reinterpret_cast<float*>(s_w);   // 4*128 floats (s_w dead)
#pragma unroll
    for (int ct = 0; ct < 4; ++ct) {
        const int ch = ct * 16 + m;
        const float bv = bias[ch];
        float s = 0.f, q = 0.f;
#pragma unroll
        for (int mt = 0; mt < 2; ++mt) {
#pragma unroll
            for (int r = 0; r < 4; ++r) {
                acc[mt][ct][r] += bv;
                const int vox = n0 + lv0 + mt * 16 + quad * 4 + r;
                if (vox < N) {
                    const float v = acc[mt][ct][r];
                    s += v;
                    q += v * v;
                }
            }
        }
        s += __shfl_xor(s, 16, 64);
        s += __shfl_xor(s, 32, 64);
        q += __shfl_xor(q, 16, 64);
        q += __shfl_xor(q, 32, 64);
        if (quad == 0) {
            s_red[wv * 128 + ch]      = s;
            s_red[wv * 128 + 64 + ch] = q;
        }
    }
    __syncthreads();
    if (threadIdx.x < 128) {
        const float v = s_red[threadIdx.x] + s_red[128 + threadIdx.x] +
                        s_red[256 + threadIdx.x] + s_red[384 + threadIdx.x];
        atomicAdd(&stats[threadIdx.x], v);     // device-scope
    }

    grid_arrive_wait(bar, (unsigned)gridDim.x);

    // broadcast final stats through LDS (agent-scope atomic loads, no L1 stale)
    if (threadIdx.x < 128)
        s_red[threadIdx.x] =
            __hip_atomic_load(&stats[threadIdx.x], __ATOMIC_ACQUIRE,
                              __HIP_MEMORY_SCOPE_AGENT);
    __syncthreads();

    // ---- BN on the register tile, store once ----
#pragma unroll
    for (int ct = 0; ct < 4; ++ct) {
        const int ch = ct * 16 + m;
        const float mu  = s_red[ch] * invN;
        const float var = s_red[64 + ch] * invN - mu * mu;
        const float rs  = rsqrtf(var + EPSV);
        const float scv = gmm[ch] * rs;
        const float shv = bet[ch] - mu * scv;
#pragma unroll
        for (int mt = 0; mt < 2; ++mt) {
#pragma unroll
            for (int r = 0; r < 4; ++r) {
                const int vox = n0 + lv0 + mt * 16 + quad * 4 + r;
                if (vox < N) {
                    const float x = fmaf(acc[mt][ct][r], scv, shv);
                    if (phase == 0) {
                        ((unsigned short*)dst)[(size_t)vox * NCH + ch] =
                            f2bf(fmaxf(x, 0.f));
                    } else {
                        ((float*)dst)[(size_t)vox * NCH + ch] =
                            fmaxf(x + resid[(size_t)vox * NCH + ch], 0.f);
                    }
                }
            }
        }
    }
}

extern "C" void kernel_launch(void* const* d_in, const int* in_sizes, int n_in,
                              void* d_out, int out_size, void* d_ws, size_t ws_size,
                              hipStream_t stream)
{
    const float* feats = (const float*)d_in[0];
    const int*   nbr   = (const int*)d_in[1];
    const float* W1    = (const float*)d_in[2];
    const float* b1    = (const float*)d_in[3];
    const float* g1    = (const float*)d_in[4];
    const float* be1   = (const float*)d_in[5];
    const float* W2    = (const float*)d_in[6];
    const float* b2    = (const float*)d_in[7];
    const float* g2    = (const float*)d_in[8];
    const float* be2   = (const float*)d_in[9];
    float* out = (float*)d_out;

    const int N  = in_sizes[0] / NCH;          // 100000
    const int NC = N * NCH;                    // 6,400,000
    const float invN = 1.0f / (float)N;

    // workspace layout
    unsigned short* fbf  = (unsigned short*)d_ws;              // [N*C] bf16
    unsigned short* hbf  = fbf + NC;                           // [N*C] bf16
    unsigned short* wt1  = hbf + NC;                           // 110592 bf16
    unsigned short* wt2  = wt1 + KOFF * 4096;                  // 110592 bf16
    float*          stat = (float*)(wt2 + KOFF * 4096);        // 256 fp32 + 2 u32
    unsigned*       bar  = (unsigned*)(stat + 256);            // 2 counters

    const int total8   = NC / 8;                               // 800000
    const int castGrid = (total8 + 255) / 256;                 // 3125
    const int prepGrid = 1 + 108 + castGrid;                   // 3234
    const int convGrid = (N + 127) / 128;                      // 782 <= 1024 resident

    prep_kernel<<<prepGrid, 256, 0, stream>>>(feats, W1, W2, fbf, wt1, wt2,
                                              stat, total8);

    // conv1 + BN1 + ReLU -> hbf (bf16)
    conv_fused<<<convGrid, 256, 0, stream>>>(fbf, nbr, wt1, b1, stat, bar,
                                             g1, be1, invN, (void*)hbf,
                                             feats, N, 0);

    // conv2 + BN2 + residual + ReLU -> out (fp32)
    conv_fused<<<convGrid, 256, 0, stream>>>(hbf, nbr, wt2, b2, stat + 128,
                                             bar + 1, g2, be2, invN,
                                             (void*)out, feats, N, 1);
}

// Round 8
// 396.304 us; speedup vs baseline: 1.8176x; 1.8176x over previous
//
#include <hip/hip_runtime.h>

#define NCH 64      // channels
#define KOFF 27     // kernel offsets
#define EPSV 1e-5f

typedef __attribute__((ext_vector_type(8))) short  bf16x8;
typedef __attribute__((ext_vector_type(4))) float  f32x4;
typedef __attribute__((ext_vector_type(8))) unsigned short u16x8;

__device__ __forceinline__ unsigned short f2bf(float x) {
    unsigned int u = __float_as_uint(x);
    u += 0x7fffu + ((u >> 16) & 1u);       // round-to-nearest-even
    return (unsigned short)(u >> 16);
}

// ---------------------------------------------------------------------------
// Fused prep: zero stats | W1->Wt1 | W2->Wt2 (B-fragment order) | feats->bf16
// Wt[(((k*2+s)*4+ct)*64+lane)*8 + j] = W[k][s*32+(lane>>4)*8+j][ct*16+(lane&15)]
// ---------------------------------------------------------------------------
__global__ __launch_bounds__(256)
void prep_kernel(const float* __restrict__ feats,
                 const float* __restrict__ W1, const float* __restrict__ W2,
                 unsigned short* __restrict__ fbf,
                 unsigned short* __restrict__ wt1, unsigned short* __restrict__ wt2,
                 float* __restrict__ stat, int total8)
{
    const int b = blockIdx.x;
    if (b == 0) {
        stat[threadIdx.x] = 0.f;           // 256 floats: stats1+stats2
        return;
    }
    if (b <= 108) {
        const float* W = (b <= 54) ? W1 : W2;
        unsigned short* Wt = (b <= 54) ? wt1 : wt2;
        const int t = (b <= 54 ? b - 1 : b - 55) * 256 + threadIdx.x; // 0..13823
        const int l  = t & 63;
        const int ct = (t >> 6) & 3;
        const int s  = (t >> 8) & 1;
        const int k  = t >> 9;
        const int d     = ct * 16 + (l & 15);
        const int cbase = s * 32 + (l >> 4) * 8;
        u16x8 o;
#pragma unroll
        for (int j = 0; j < 8; ++j)
            o[j] = f2bf(W[(size_t)k * 4096 + (size_t)(cbase + j) * 64 + d]);
        reinterpret_cast<u16x8*>(Wt)[t] = o;
        return;
    }
    const int idx = (b - 109) * 256 + threadIdx.x;
    if (idx >= total8) return;
    const float4* xp = reinterpret_cast<const float4*>(feats) + (size_t)idx * 2;
    const float4 a = xp[0], c = xp[1];
    u16x8 o;
    o[0] = f2bf(a.x); o[1] = f2bf(a.y); o[2] = f2bf(a.z); o[3] = f2bf(a.w);
    o[4] = f2bf(c.x); o[5] = f2bf(c.y); o[6] = f2bf(c.z); o[7] = f2bf(c.w);
    reinterpret_cast<u16x8*>(fbf)[idx] = o;
}

// ---------------------------------------------------------------------------
// Gathered conv via MFMA (r5/r7 verified core: 4 waves/block, 128 voxels,
// weights via LDS in 2-offset 16KB chunks, A register-double-buffered).
// PHASE 0 (conv1): gather fbf, conv+bias -> write RAW bf16 y1 (no BN) +
//   device-scope atomic stats. PHASE 1 (conv2): gather raw y1 and apply
//   BN1 affine + ReLU **in registers on the gathered fragments** (sc/sh
//   from conv1's stats, live in 32 VGPRs), conv+bias -> fp32 y2 + atomic
//   stats. No reduce kernels, no fp32 intermediate round-trip, no grid
//   barrier (r7 lesson: residency margins too thin for spin barriers).
// ---------------------------------------------------------------------------
template <int PHASE>
__global__ __launch_bounds__(256, 4)
void conv_kernel(const unsigned short* __restrict__ fin,
                 const int* __restrict__ nbr,
                 const unsigned short* __restrict__ Wt,
                 const float* __restrict__ bias,
                 const float* __restrict__ statIn,   // PHASE1: conv1 stats
                 const float* __restrict__ gmm,      // PHASE1: BN1 gamma
                 const float* __restrict__ bet,      // PHASE1: BN1 beta
                 float* __restrict__ statOut,
                 float invN, void* __restrict__ dst, int N)
{
    __shared__ int            s_idx[128 * KOFF];   // 13824 B
    __shared__ unsigned short s_w[2 * 4096];       // 16384 B (2 weight tiles)

    const int lane = threadIdx.x & 63;
    const int wv   = threadIdx.x >> 6;        // 0..3
    const int n0   = blockIdx.x * 128;
    const int m    = lane & 15;
    const int quad = lane >> 4;

    // PHASE1: per-lane BN1 affine params for the 16 channels this lane gathers
    float scA[2][8], shA[2][8];
    if constexpr (PHASE == 1) {
#pragma unroll
        for (int ss = 0; ss < 2; ++ss)
#pragma unroll
            for (int j = 0; j < 8; ++j) {
                const int ch = ss * 32 + quad * 8 + j;
                const float mu  = statIn[ch] * invN;
                const float var = statIn[64 + ch] * invN - mu * mu;
                const float rs  = rsqrtf(var + EPSV);
                scA[ss][j] = gmm[ch] * rs;
                shA[ss][j] = bet[ch] - mu * scA[ss][j];
            }
    }

    {   // stage 3456 ints cooperatively, pre-scaled to byte offsets
        const int rem  = N - n0;
        const int maxi = (rem < 128 ? rem : 128) * KOFF;
        const int* nb  = nbr + (size_t)n0 * KOFF;
        for (int p = threadIdx.x; p < 128 * KOFF; p += 256)
            s_idx[p] = ((p < maxi) ? nb[p] : 0) * (NCH * 2);
    }
    __syncthreads();

    f32x4 acc[2][4];
#pragma unroll
    for (int mt = 0; mt < 2; ++mt)
#pragma unroll
        for (int ct = 0; ct < 4; ++ct) acc[mt][ct] = (f32x4){0.f, 0.f, 0.f, 0.f};

    bf16x8 A[2][2][2];   // [parity][m-tile][s] : double-buffered
    bf16x8 B[2][4];      // [s][ct] from LDS
    const char* finB = (const char*)fin;
    const int lv0 = wv * 32;

#define LOADA(kk, par)                                                       \
    {                                                                        \
        _Pragma("unroll")                                                    \
        for (int mt = 0; mt < 2; ++mt) {                                     \
            const int ofs = s_idx[(lv0 + mt * 16 + m) * KOFF + (kk)];        \
            const char* fp = finB + ofs + quad * 16;                         \
            A[par][mt][0] = *reinterpret_cast<const bf16x8*>(fp);            \
            A[par][mt][1] = *reinterpret_cast<const bf16x8*>(fp + 64);       \
        }                                                                    \
    }

// PHASE1 only: BN1 affine + ReLU on the gathered fragment (in registers),
// applied exactly once, just before the fragment's single MFMA use.
#define XFORM(par)                                                           \
    if constexpr (PHASE == 1) {                                              \
        _Pragma("unroll")                                                    \
        for (int mt = 0; mt < 2; ++mt)                                       \
            _Pragma("unroll")                                                \
            for (int ss = 0; ss < 2; ++ss)                                   \
                _Pragma("unroll")                                            \
                for (int j = 0; j < 8; ++j) {                                \
                    const float x = __uint_as_float(                         \
                        ((unsigned)(unsigned short)A[par][mt][ss][j]) << 16);\
                    const float z =                                          \
                        fmaxf(fmaf(x, scA[ss][j], shA[ss][j]), 0.f);         \
                    A[par][mt][ss][j] = (short)f2bf(z);                      \
                }                                                            \
    }

#define LOADB_LDS(sl)                                                        \
    {                                                                        \
        const unsigned short* wp = s_w + (sl) * 4096 + lane * 8;             \
        _Pragma("unroll")                                                    \
        for (int s = 0; s < 2; ++s)                                          \
            _Pragma("unroll")                                                \
            for (int ct = 0; ct < 4; ++ct)                                   \
                B[s][ct] =                                                   \
                    *reinterpret_cast<const bf16x8*>(wp + (s * 4 + ct) * 512);\
    }

#define DOMFMA(par)                                                          \
    {                                                                        \
        _Pragma("unroll")                                                    \
        for (int mt = 0; mt < 2; ++mt)                                       \
            _Pragma("unroll")                                                \
            for (int s = 0; s < 2; ++s)                                      \
                _Pragma("unroll")                                            \
                for (int ct = 0; ct < 4; ++ct)                               \
                    acc[mt][ct] = __builtin_amdgcn_mfma_f32_16x16x32_bf16(   \
                        A[par][mt][s], B[s][ct], acc[mt][ct], 0, 0, 0);      \
    }

    LOADA(0, 0);                               // first A prefetch in flight

    // 13 chunks of 2 offsets (k = kb, kb+1); parity position-static.
#pragma unroll 1
    for (int kb = 0; kb < KOFF - 1; kb += 2) {
        {   // stage 2 weight tiles: 16KB coalesced by 256 threads
            const u16x8* gw = reinterpret_cast<const u16x8*>(Wt) + (size_t)kb * 512;
            u16x8* lw = reinterpret_cast<u16x8*>(s_w);
#pragma unroll
            for (int i = 0; i < 4; ++i)        // 4*256 = 1024 = 2*512 units
                lw[threadIdx.x + i * 256] = gw[threadIdx.x + i * 256];
        }
        __syncthreads();                       // s_w ready

        LOADA(kb + 1, 1);
        LOADB_LDS(0);
        __builtin_amdgcn_sched_barrier(0);
        XFORM(0);
        DOMFMA(0);

        LOADA(kb + 2, 0);                      // kb+2 <= 26 always valid
        LOADB_LDS(1);
        __builtin_amdgcn_sched_barrier(0);
        XFORM(1);
        DOMFMA(1);

        __syncthreads();                       // done with s_w
    }
    {   // tail: k = 26 (A already prefetched, parity 0)
        const u16x8* gw = reinterpret_cast<const u16x8*>(Wt) + (size_t)26 * 512;
        u16x8* lw = reinterpret_cast<u16x8*>(s_w);
#pragma unroll
        for (int i = 0; i < 2; ++i)
            lw[threadIdx.x + i * 256] = gw[threadIdx.x + i * 256];
        __syncthreads();
        LOADB_LDS(0);
        __builtin_amdgcn_sched_barrier(0);
        XFORM(0);
        DOMFMA(0);
        __syncthreads();
    }
#undef LOADA
#undef XFORM
#undef LOADB_LDS
#undef DOMFMA

    // ---- epilogue: bias, raw store (bf16 or fp32), block stats -> atomics ----
    float* s_red = reinterpret_cast<float*>(s_w);   // 4*128 floats (s_w dead)
#pragma unroll
    for (int ct = 0; ct < 4; ++ct) {
        const int ch = ct * 16 + m;
        const float bv = bias[ch];
        float s = 0.f, q = 0.f;
#pragma unroll
        for (int mt = 0; mt < 2; ++mt) {
#pragma unroll
            for (int r = 0; r < 4; ++r) {
                const int vox = n0 + lv0 + mt * 16 + quad * 4 + r;
                if (vox < N) {
                    const float v = acc[mt][ct][r] + bv;
                    if constexpr (PHASE == 0)
                        ((unsigned short*)dst)[(size_t)vox * NCH + ch] = f2bf(v);
                    else
                        ((float*)dst)[(size_t)vox * NCH + ch] = v;
                    s += v;
                    q += v * v;
                }
            }
        }
        s += __shfl_xor(s, 16, 64);
        s += __shfl_xor(s, 32, 64);
        q += __shfl_xor(q, 16, 64);
        q += __shfl_xor(q, 32, 64);
        if (quad == 0) {
            s_red[wv * 128 + ch]      = s;
            s_red[wv * 128 + 64 + ch] = q;
        }
    }
    __syncthreads();
    if (threadIdx.x < 128) {
        const float v = s_red[threadIdx.x] + s_red[128 + threadIdx.x] +
                        s_red[256 + threadIdx.x] + s_red[384 + threadIdx.x];
        atomicAdd(&statOut[threadIdx.x], v);   // device-scope, 1 per ch per block
    }
}

// ---------------------------------------------------------------------------
// BN2 + residual + ReLU: y2 fp32 + feats -> out. Stats read directly from
// the atomically-accumulated stat buffer (no reduce kernel).
// ---------------------------------------------------------------------------
__global__ __launch_bounds__(256)
void bn_res_relu_kernel(const float* __restrict__ x, const float* __restrict__ feats,
                        const float* __restrict__ sums, const float* __restrict__ gmm,
                        const float* __restrict__ bet, float invN,
                        float* __restrict__ out, int total4)
{
    const int idx = blockIdx.x * blockDim.x + threadIdx.x;
    if (idx >= total4) return;
    const float4 v = reinterpret_cast<const float4*>(x)[idx];
    const float4 f = reinterpret_cast<const float4*>(feats)[idx];
    const int c0 = (idx & 15) * 4;
    float sc[4], sh[4];
#pragma unroll
    for (int i = 0; i < 4; ++i) {
        const int c = c0 + i;
        const float mu  = sums[c] * invN;
        const float var = sums[64 + c] * invN - mu * mu;
        const float rs  = rsqrtf(var + EPSV);
        sc[i] = gmm[c] * rs;
        sh[i] = bet[c] - mu * sc[i];
    }
    float4 o;
    o.x = fmaxf(fmaf(v.x, sc[0], sh[0]) + f.x, 0.f);
    o.y = fmaxf(fmaf(v.y, sc[1], sh[1]) + f.y, 0.f);
    o.z = fmaxf(fmaf(v.z, sc[2], sh[2]) + f.z, 0.f);
    o.w = fmaxf(fmaf(v.w, sc[3], sh[3]) + f.w, 0.f);
    reinterpret_cast<float4*>(out)[idx] = o;
}

extern "C" void kernel_launch(void* const* d_in, const int* in_sizes, int n_in,
                              void* d_out, int out_size, void* d_ws, size_t ws_size,
                              hipStream_t stream)
{
    const float* feats = (const float*)d_in[0];
    const int*   nbr   = (const int*)d_in[1];
    const float* W1    = (const float*)d_in[2];
    const float* b1    = (const float*)d_in[3];
    const float* g1    = (const float*)d_in[4];
    const float* be1   = (const float*)d_in[5];
    const float* W2    = (const float*)d_in[6];
    const float* b2    = (const float*)d_in[7];
    const float* g2    = (const float*)d_in[8];
    const float* be2   = (const float*)d_in[9];
    float* out = (float*)d_out;

    const int N  = in_sizes[0] / NCH;          // 100000
    const int NC = N * NCH;                    // 6,400,000
    const float invN = 1.0f / (float)N;

    // workspace layout
    float*          y2   = (float*)d_ws;                       // [N*C] fp32 (conv2 raw)
    unsigned short* fbf  = (unsigned short*)(y2 + NC);         // [N*C] bf16
    unsigned short* ybf  = fbf + NC;                           // [N*C] bf16 (conv1 raw)
    unsigned short* wt1  = ybf + NC;                           // 110592 bf16
    unsigned short* wt2  = wt1 + KOFF * 4096;                  // 110592 bf16
    float*          stat = (float*)(wt2 + KOFF * 4096);        // 256 fp32

    const int total8   = NC / 8;                               // 800000
    const int castGrid = (total8 + 255) / 256;                 // 3125
    const int prepGrid = 1 + 108 + castGrid;                   // 3234
    const int convGrid = (N + 127) / 128;                      // 782

    prep_kernel<<<prepGrid, 256, 0, stream>>>(feats, W1, W2, fbf, wt1, wt2,
                                              stat, total8);

    // conv1 -> raw bf16 y1 + stats1 (atomic)
    conv_kernel<0><<<convGrid, 256, 0, stream>>>(fbf, nbr, wt1, b1,
                                                 nullptr, nullptr, nullptr,
                                                 stat, invN, (void*)ybf, N);

    // conv2 (BN1+ReLU applied on gathered fragments) -> fp32 y2 + stats2
    conv_kernel<1><<<convGrid, 256, 0, stream>>>(ybf, nbr, wt2, b2,
                                                 stat, g1, be1,
                                                 stat + 128, invN, (void*)y2, N);

    // BN2 + residual + ReLU -> out
    bn_res_relu_kernel<<<(NC / 4 + 255) / 256, 256, 0, stream>>>(
        y2, feats, stat + 128, g2, be2, invN, out, NC / 4);
}

// Round 10
// 299.093 us; speedup vs baseline: 2.4083x; 1.3250x over previous
//
#include <hip/hip_runtime.h>

#define NCH 64      // channels
#define KOFF 27     // kernel offsets
#define EPSV 1e-5f

typedef __attribute__((ext_vector_type(8))) short  bf16x8;
typedef __attribute__((ext_vector_type(4))) float  f32x4;
typedef __attribute__((ext_vector_type(8))) unsigned short u16x8;

__device__ __forceinline__ unsigned short f2bf(float x) {
    unsigned int u = __float_as_uint(x);
    u += 0x7fffu + ((u >> 16) & 1u);       // round-to-nearest-even
    return (unsigned short)(u >> 16);
}

// Stats layout (line-padded to kill TCC atomic contention):
//   sum of channel c   at stat[c * 16]          (one fp32 per 64B line)
//   sumsq of channel c at stat[(64 + c) * 16]
// Each conv phase uses a 2048-float (8KB) half.

// ---------------------------------------------------------------------------
// Fused prep: zero stats | W1->Wt1 | W2->Wt2 (B-fragment order) | feats->bf16
// Wt[(((k*2+s)*4+ct)*64+lane)*8 + j] = W[k][s*32+(lane>>4)*8+j][ct*16+(lane&15)]
// ---------------------------------------------------------------------------
__global__ __launch_bounds__(256)
void prep_kernel(const float* __restrict__ feats,
                 const float* __restrict__ W1, const float* __restrict__ W2,
                 unsigned short* __restrict__ fbf,
                 unsigned short* __restrict__ wt1, unsigned short* __restrict__ wt2,
                 float* __restrict__ stat, int total8)
{
    const int b = blockIdx.x;
    if (b == 0) {
#pragma unroll
        for (int i = 0; i < 16; ++i)           // 4096 floats: both stat halves
            stat[threadIdx.x + i * 256] = 0.f;
        return;
    }
    if (b <= 108) {
        const float* W = (b <= 54) ? W1 : W2;
        unsigned short* Wt = (b <= 54) ? wt1 : wt2;
        const int t = (b <= 54 ? b - 1 : b - 55) * 256 + threadIdx.x; // 0..13823
        const int l  = t & 63;
        const int ct = (t >> 6) & 3;
        const int s  = (t >> 8) & 1;
        const int k  = t >> 9;
        const int d     = ct * 16 + (l & 15);
        const int cbase = s * 32 + (l >> 4) * 8;
        u16x8 o;
#pragma unroll
        for (int j = 0; j < 8; ++j)
            o[j] = f2bf(W[(size_t)k * 4096 + (size_t)(cbase + j) * 64 + d]);
        reinterpret_cast<u16x8*>(Wt)[t] = o;
        return;
    }
    const int idx = (b - 109) * 256 + threadIdx.x;
    if (idx >= total8) return;
    const float4* xp = reinterpret_cast<const float4*>(feats) + (size_t)idx * 2;
    const float4 a = xp[0], c = xp[1];
    u16x8 o;
    o[0] = f2bf(a.x); o[1] = f2bf(a.y); o[2] = f2bf(a.z); o[3] = f2bf(a.w);
    o[4] = f2bf(c.x); o[5] = f2bf(c.y); o[6] = f2bf(c.z); o[7] = f2bf(c.w);
    reinterpret_cast<u16x8*>(fbf)[idx] = o;
}

// ---------------------------------------------------------------------------
// Gathered conv via MFMA 16x16x32 bf16 — r5's PROVEN core verbatim (4 waves/
// block, 128 voxels, weights via LDS in 9 chunks of 3 offsets = 24KB, A
// register-double-buffered, fully-unrolled chunk loop, 77us measured).
// Epilogue only changed: wave-uniform fp32out flag picks fp32 (conv2) or
// bf16 (conv1) stores; block-reduced stats go via ONE atomicAdd per channel
// per block to the line-padded stat array (no reduce kernels).
// ---------------------------------------------------------------------------
__global__ __launch_bounds__(256, 4)
void conv_mfma_kernel(const unsigned short* __restrict__ fin,
                      const int* __restrict__ nbr,
                      const unsigned short* __restrict__ Wt,
                      const float* __restrict__ bias,
                      float* __restrict__ statOut,
                      void* __restrict__ dst, int N, int fp32out)
{
    __shared__ int            s_idx[128 * KOFF];   // 13824 B
    __shared__ unsigned short s_w[3 * 4096];       // 24576 B (3 weight tiles)

    const int lane = threadIdx.x & 63;
    const int wv   = threadIdx.x >> 6;        // 0..3
    const int n0   = blockIdx.x * 128;
    const int m    = lane & 15;
    const int quad = lane >> 4;

    {   // stage 3456 ints cooperatively, pre-scaled to byte offsets
        const int rem  = N - n0;
        const int maxi = (rem < 128 ? rem : 128) * KOFF;
        const int* nb  = nbr + (size_t)n0 * KOFF;
        for (int p = threadIdx.x; p < 128 * KOFF; p += 256)
            s_idx[p] = ((p < maxi) ? nb[p] : 0) * (NCH * 2);
    }
    __syncthreads();

    f32x4 acc[2][4];
#pragma unroll
    for (int mt = 0; mt < 2; ++mt)
#pragma unroll
        for (int ct = 0; ct < 4; ++ct) acc[mt][ct] = (f32x4){0.f, 0.f, 0.f, 0.f};

    bf16x8 A[2][2][2];   // [k&1][m-tile][s] : 32 VGPR, double-buffered
    bf16x8 B[2][4];      // [s][ct] from LDS : 32 VGPR
    const char* finB = (const char*)fin;
    const int lv0 = wv * 32;                  // wave's local voxel base

#define LOADA(kk)                                                            \
    {                                                                        \
        _Pragma("unroll")                                                    \
        for (int mt = 0; mt < 2; ++mt) {                                     \
            const int ofs = s_idx[(lv0 + mt * 16 + m) * KOFF + (kk)];        \
            const char* fp = finB + ofs + quad * 16;                         \
            A[(kk) & 1][mt][0] = *reinterpret_cast<const bf16x8*>(fp);       \
            A[(kk) & 1][mt][1] = *reinterpret_cast<const bf16x8*>(fp + 64);  \
        }                                                                    \
    }

#define LOADB_LDS(kk)                                                        \
    {                                                                        \
        const unsigned short* wp = s_w + (kk) * 4096 + lane * 8;             \
        _Pragma("unroll")                                                    \
        for (int s = 0; s < 2; ++s)                                          \
            _Pragma("unroll")                                                \
            for (int ct = 0; ct < 4; ++ct)                                   \
                B[s][ct] =                                                   \
                    *reinterpret_cast<const bf16x8*>(wp + (s * 4 + ct) * 512);\
    }

#define DOMFMA(kk)                                                           \
    {                                                                        \
        _Pragma("unroll")                                                    \
        for (int mt = 0; mt < 2; ++mt)                                       \
            _Pragma("unroll")                                                \
            for (int s = 0; s < 2; ++s)                                      \
                _Pragma("unroll")                                            \
                for (int ct = 0; ct < 4; ++ct)                               \
                    acc[mt][ct] = __builtin_amdgcn_mfma_f32_16x16x32_bf16(   \
                        A[(kk) & 1][mt][s], B[s][ct], acc[mt][ct], 0, 0, 0); \
    }

    LOADA(0);                                  // first A prefetch in flight

#pragma unroll
    for (int c = 0; c < 9; ++c) {
        const int kb = c * 3;                  // compile-time (full unroll)

        // ---- stage weight chunk: 3*8KB, coalesced, all 256 threads ----
        {
            const u16x8* gw = reinterpret_cast<const u16x8*>(
                Wt + (size_t)kb * 4096);
            u16x8* lw = reinterpret_cast<u16x8*>(s_w);
#pragma unroll
            for (int i = 0; i < 6; ++i)        // 6*256 = 1536 = 3*512 units
                lw[threadIdx.x + i * 256] = gw[threadIdx.x + i * 256];
        }
        __syncthreads();                       // s_w ready

        // ---- 3 k-steps, A double-buffered by global parity, B from LDS ----
        LOADA(kb + 1);
        LOADB_LDS(0);
        __builtin_amdgcn_sched_barrier(0);
        DOMFMA(kb);

        LOADA(kb + 2);
        LOADB_LDS(1);
        __builtin_amdgcn_sched_barrier(0);
        DOMFMA(kb + 1);

        if (c < 8) LOADA(kb + 3);              // prefetch next chunk's first A
        LOADB_LDS(2);
        __builtin_amdgcn_sched_barrier(0);
        DOMFMA(kb + 2);

        __syncthreads();                       // all waves done with s_w
    }
#undef LOADA
#undef LOADB_LDS
#undef DOMFMA

    // ---- epilogue: bias, store (fp32 or bf16), block stats -> padded atomics
    float* s_red = reinterpret_cast<float*>(s_w);   // 4*128 floats (s_w dead)

#define EPI(STORE_STMT)                                                      \
    _Pragma("unroll")                                                        \
    for (int ct = 0; ct < 4; ++ct) {                                         \
        const int ch = ct * 16 + m;                                          \
        const float bv = bias[ch];                                           \
        float s = 0.f, q = 0.f;                                              \
        _Pragma("unroll")                                                    \
        for (int mt = 0; mt < 2; ++mt) {                                     \
            _Pragma("unroll")                                                \
            for (int r = 0; r < 4; ++r) {                                    \
                const int vox = n0 + lv0 + mt * 16 + quad * 4 + r;           \
                if (vox < N) {                                               \
                    const float v = acc[mt][ct][r] + bv;                     \
                    STORE_STMT;                                              \
                    s += v;                                                  \
                    q += v * v;                                              \
                }                                                            \
            }                                                                \
        }                                                                    \
        s += __shfl_xor(s, 16, 64);                                          \
        s += __shfl_xor(s, 32, 64);                                          \
        q += __shfl_xor(q, 16, 64);                                          \
        q += __shfl_xor(q, 32, 64);                                          \
        if (quad == 0) {                                                     \
            s_red[wv * 128 + ch]      = s;                                   \
            s_red[wv * 128 + 64 + ch] = q;                                   \
        }                                                                    \
    }

    if (fp32out) {
        EPI(((float*)dst)[(size_t)vox * NCH + ch] = v)
    } else {
        EPI(((unsigned short*)dst)[(size_t)vox * NCH + ch] = f2bf(v))
    }
#undef EPI

    __syncthreads();
    if (threadIdx.x < 128) {
        const float v = s_red[threadIdx.x] + s_red[128 + threadIdx.x] +
                        s_red[256 + threadIdx.x] + s_red[384 + threadIdx.x];
        // one fp32 per 64B line: atomics parallelize across TCC channels
        atomicAdd(&statOut[threadIdx.x * 16], v);
    }
}

// ---------------------------------------------------------------------------
// BN1 + ReLU, bf16 in -> bf16 out (conv2's gather input). 8 elems/thread.
// Stats read directly from the line-padded atomic accumulator.
// ---------------------------------------------------------------------------
__global__ __launch_bounds__(256)
void bn_relu_bf16_kernel(const unsigned short* __restrict__ x,
                         const float* __restrict__ sums,
                         const float* __restrict__ gmm, const float* __restrict__ bet,
                         float invN, unsigned short* __restrict__ y, int total8)
{
    const int idx = blockIdx.x * 256 + threadIdx.x;
    if (idx >= total8) return;
    const int c0 = (idx & 7) * 8;
    const u16x8 v = reinterpret_cast<const u16x8*>(x)[idx];
    u16x8 o;
#pragma unroll
    for (int i = 0; i < 8; ++i) {
        const int c = c0 + i;
        const float mu  = sums[c * 16] * invN;
        const float var = sums[1024 + c * 16] * invN - mu * mu;
        const float rs  = rsqrtf(var + EPSV);
        const float sc  = gmm[c] * rs;
        const float sh  = bet[c] - mu * sc;
        const float xv  = __uint_as_float(((unsigned)v[i]) << 16);
        o[i] = f2bf(fmaxf(fmaf(xv, sc, sh), 0.f));
    }
    reinterpret_cast<u16x8*>(y)[idx] = o;
}

// ---------------------------------------------------------------------------
// BN2 + residual + ReLU: y2 fp32 + feats -> out fp32.
// ---------------------------------------------------------------------------
__global__ __launch_bounds__(256)
void bn_res_relu_kernel(const float* __restrict__ x, const float* __restrict__ feats,
                        const float* __restrict__ sums, const float* __restrict__ gmm,
                        const float* __restrict__ bet, float invN,
                        float* __restrict__ out, int total4)
{
    const int idx = blockIdx.x * blockDim.x + threadIdx.x;
    if (idx >= total4) return;
    const float4 v = reinterpret_cast<const float4*>(x)[idx];
    const float4 f = reinterpret_cast<const float4*>(feats)[idx];
    const int c0 = (idx & 15) * 4;
    float sc[4], sh[4];
#pragma unroll
    for (int i = 0; i < 4; ++i) {
        const int c = c0 + i;
        const float mu  = sums[c * 16] * invN;
        const float var = sums[1024 + c * 16] * invN - mu * mu;
        const float rs  = rsqrtf(var + EPSV);
        sc[i] = gmm[c] * rs;
        sh[i] = bet[c] - mu * sc[i];
    }
    float4 o;
    o.x = fmaxf(fmaf(v.x, sc[0], sh[0]) + f.x, 0.f);
    o.y = fmaxf(fmaf(v.y, sc[1], sh[1]) + f.y, 0.f);
    o.z = fmaxf(fmaf(v.z, sc[2], sh[2]) + f.z, 0.f);
    o.w = fmaxf(fmaf(v.w, sc[3], sh[3]) + f.w, 0.f);
    reinterpret_cast<float4*>(out)[idx] = o;
}

extern "C" void kernel_launch(void* const* d_in, const int* in_sizes, int n_in,
                              void* d_out, int out_size, void* d_ws, size_t ws_size,
                              hipStream_t stream)
{
    const float* feats = (const float*)d_in[0];
    const int*   nbr   = (const int*)d_in[1];
    const float* W1    = (const float*)d_in[2];
    const float* b1    = (const float*)d_in[3];
    const float* g1    = (const float*)d_in[4];
    const float* be1   = (const float*)d_in[5];
    const float* W2    = (const float*)d_in[6];
    const float* b2    = (const float*)d_in[7];
    const float* g2    = (const float*)d_in[8];
    const float* be2   = (const float*)d_in[9];
    float* out = (float*)d_out;

    const int N  = in_sizes[0] / NCH;          // 100000
    const int NC = N * NCH;                    // 6,400,000
    const float invN = 1.0f / (float)N;

    // workspace layout with liveness aliasing (peak ~38.9 MB, below every
    // previously-passing round):
    //   [0,  NC bf16)          fbf  (feats bf16; dead after conv1)
    //   [NC, 2NC bf16)         y1   (conv1 raw bf16; dead after bn_relu)
    //   y2 fp32 OVERLAYS fbf+y1 (exactly 2NC bf16 = NC fp32 bytes); conv2
    //   writes it after both are dead.
    //   then h1, wt1, wt2, stat.
    unsigned short* fbf  = (unsigned short*)d_ws;              // [N*C] bf16
    unsigned short* y1   = fbf + NC;                           // [N*C] bf16
    float*          y2   = (float*)d_ws;                       // [N*C] fp32 (alias)
    unsigned short* h1   = y1 + NC;                            // [N*C] bf16 (bn1 out)
    unsigned short* wt1  = h1 + NC;                            // 110592 bf16
    unsigned short* wt2  = wt1 + KOFF * 4096;                  // 110592 bf16
    float*          stat = (float*)(wt2 + KOFF * 4096);        // 4096 fp32 padded

    const int total8   = NC / 8;                               // 800000
    const int castGrid = (total8 + 255) / 256;                 // 3125
    const int prepGrid = 1 + 108 + castGrid;                   // 3234
    const int convGrid = (N + 127) / 128;                      // 782

    prep_kernel<<<prepGrid, 256, 0, stream>>>(feats, W1, W2, fbf, wt1, wt2,
                                              stat, total8);

    // conv1 -> raw bf16 y1 + stats1 (padded atomics)
    conv_mfma_kernel<<<convGrid, 256, 0, stream>>>(fbf, nbr, wt1, b1, stat,
                                                   (void*)y1, N, 0);

    // BN1 + ReLU: y1 bf16 -> h1 bf16   (fbf becomes dead here too)
    bn_relu_bf16_kernel<<<castGrid, 256, 0, stream>>>(y1, stat, g1, be1, invN,
                                                      h1, total8);

    // conv2 -> raw fp32 y2 (overlays dead fbf+y1) + stats2 (padded atomics)
    conv_mfma_kernel<<<convGrid, 256, 0, stream>>>(h1, nbr, wt2, b2,
                                                   stat + 2048, (void*)y2, N, 1);

    // BN2 + residual + ReLU -> out
    bn_res_relu_kernel<<<(NC / 4 + 255) / 256, 256, 0, stream>>>(
        y2, feats, stat + 2048, g2, be2, invN, out, NC / 4);
}

// Round 11
// 267.955 us; speedup vs baseline: 2.6882x; 1.1162x over previous
//
#include <hip/hip_runtime.h>

#define NCH 64      // channels
#define KOFF 27     // kernel offsets
#define EPSV 1e-5f

typedef __attribute__((ext_vector_type(8))) short  bf16x8;
typedef __attribute__((ext_vector_type(4))) float  f32x4;
typedef __attribute__((ext_vector_type(8))) unsigned short u16x8;

__device__ __forceinline__ unsigned short f2bf(float x) {
    unsigned int u = __float_as_uint(x);
    u += 0x7fffu + ((u >> 16) & 1u);       // round-to-nearest-even
    return (unsigned short)(u >> 16);
}

// Stats layout: 8 contention-spread copies per phase, line-padded.
//   copy j (j = blockIdx & 7), channel stat c (0..127; c<64 sum, c>=64 sumsq)
//   lives at stats[j * 2048 + c * 16]   (one fp32 per 64B line)
// Phase base: stat + phase * 16384. Consumers fold the 8 copies via LDS.

// ---------------------------------------------------------------------------
// Fused prep: zero stats | W1->Wt1 | W2->Wt2 (B-fragment order) | feats->bf16
// Wt[(((k*2+s)*4+ct)*64+lane)*8 + j] = W[k][s*32+(lane>>4)*8+j][ct*16+(lane&15)]
// ---------------------------------------------------------------------------
__global__ __launch_bounds__(256)
void prep_kernel(const float* __restrict__ feats,
                 const float* __restrict__ W1, const float* __restrict__ W2,
                 unsigned short* __restrict__ fbf,
                 unsigned short* __restrict__ wt1, unsigned short* __restrict__ wt2,
                 float* __restrict__ stat, int total8)
{
    const int b = blockIdx.x;
    if (b == 0) {
        // zero 32768 floats (2 phases x 8 copies x 2048) as float4
        float4* s4 = reinterpret_cast<float4*>(stat);
#pragma unroll
        for (int i = 0; i < 32; ++i)
            s4[threadIdx.x + i * 256] = (float4){0.f, 0.f, 0.f, 0.f};
        return;
    }
    if (b <= 108) {
        const float* W = (b <= 54) ? W1 : W2;
        unsigned short* Wt = (b <= 54) ? wt1 : wt2;
        const int t = (b <= 54 ? b - 1 : b - 55) * 256 + threadIdx.x; // 0..13823
        const int l  = t & 63;
        const int ct = (t >> 6) & 3;
        const int s  = (t >> 8) & 1;
        const int k  = t >> 9;
        const int d     = ct * 16 + (l & 15);
        const int cbase = s * 32 + (l >> 4) * 8;
        u16x8 o;
#pragma unroll
        for (int j = 0; j < 8; ++j)
            o[j] = f2bf(W[(size_t)k * 4096 + (size_t)(cbase + j) * 64 + d]);
        reinterpret_cast<u16x8*>(Wt)[t] = o;
        return;
    }
    const int idx = (b - 109) * 256 + threadIdx.x;
    if (idx >= total8) return;
    const float4* xp = reinterpret_cast<const float4*>(feats) + (size_t)idx * 2;
    const float4 a = xp[0], c = xp[1];
    u16x8 o;
    o[0] = f2bf(a.x); o[1] = f2bf(a.y); o[2] = f2bf(a.z); o[3] = f2bf(a.w);
    o[4] = f2bf(c.x); o[5] = f2bf(c.y); o[6] = f2bf(c.z); o[7] = f2bf(c.w);
    reinterpret_cast<u16x8*>(fbf)[idx] = o;
}

// ---------------------------------------------------------------------------
// Gathered conv via MFMA 16x16x32 bf16 — r5's PROVEN core verbatim (4 waves/
// block, 128 voxels, weights via LDS in 9 chunks of 3 offsets = 24KB, A
// register-double-buffered, fully-unrolled chunk loop, 77us measured).
// Epilogue: wave-uniform fp32out flag; block-reduced stats -> ONE atomicAdd
// per channel per block into stats copy (blockIdx & 7): contention per
// address ~98 instead of 782 (r10's +10us/conv atomic tail).
// ---------------------------------------------------------------------------
__global__ __launch_bounds__(256, 4)
void conv_mfma_kernel(const unsigned short* __restrict__ fin,
                      const int* __restrict__ nbr,
                      const unsigned short* __restrict__ Wt,
                      const float* __restrict__ bias,
                      float* __restrict__ statOut,
                      void* __restrict__ dst, int N, int fp32out)
{
    __shared__ int            s_idx[128 * KOFF];   // 13824 B
    __shared__ unsigned short s_w[3 * 4096];       // 24576 B (3 weight tiles)

    const int lane = threadIdx.x & 63;
    const int wv   = threadIdx.x >> 6;        // 0..3
    const int n0   = blockIdx.x * 128;
    const int m    = lane & 15;
    const int quad = lane >> 4;

    {   // stage 3456 ints cooperatively, pre-scaled to byte offsets
        const int rem  = N - n0;
        const int maxi = (rem < 128 ? rem : 128) * KOFF;
        const int* nb  = nbr + (size_t)n0 * KOFF;
        for (int p = threadIdx.x; p < 128 * KOFF; p += 256)
            s_idx[p] = ((p < maxi) ? nb[p] : 0) * (NCH * 2);
    }
    __syncthreads();

    f32x4 acc[2][4];
#pragma unroll
    for (int mt = 0; mt < 2; ++mt)
#pragma unroll
        for (int ct = 0; ct < 4; ++ct) acc[mt][ct] = (f32x4){0.f, 0.f, 0.f, 0.f};

    bf16x8 A[2][2][2];   // [k&1][m-tile][s] : 32 VGPR, double-buffered
    bf16x8 B[2][4];      // [s][ct] from LDS : 32 VGPR
    const char* finB = (const char*)fin;
    const int lv0 = wv * 32;                  // wave's local voxel base

#define LOADA(kk)                                                            \
    {                                                                        \
        _Pragma("unroll")                                                    \
        for (int mt = 0; mt < 2; ++mt) {                                     \
            const int ofs = s_idx[(lv0 + mt * 16 + m) * KOFF + (kk)];        \
            const char* fp = finB + ofs + quad * 16;                         \
            A[(kk) & 1][mt][0] = *reinterpret_cast<const bf16x8*>(fp);       \
            A[(kk) & 1][mt][1] = *reinterpret_cast<const bf16x8*>(fp + 64);  \
        }                                                                    \
    }

#define LOADB_LDS(kk)                                                        \
    {                                                                        \
        const unsigned short* wp = s_w + (kk) * 4096 + lane * 8;             \
        _Pragma("unroll")                                                    \
        for (int s = 0; s < 2; ++s)                                          \
            _Pragma("unroll")                                                \
            for (int ct = 0; ct < 4; ++ct)                                   \
                B[s][ct] =                                                   \
                    *reinterpret_cast<const bf16x8*>(wp + (s * 4 + ct) * 512);\
    }

#define DOMFMA(kk)                                                           \
    {                                                                        \
        _Pragma("unroll")                                                    \
        for (int mt = 0; mt < 2; ++mt)                                       \
            _Pragma("unroll")                                                \
            for (int s = 0; s < 2; ++s)                                      \
                _Pragma("unroll")                                            \
                for (int ct = 0; ct < 4; ++ct)                               \
                    acc[mt][ct] = __builtin_amdgcn_mfma_f32_16x16x32_bf16(   \
                        A[(kk) & 1][mt][s], B[s][ct], acc[mt][ct], 0, 0, 0); \
    }

    LOADA(0);                                  // first A prefetch in flight

#pragma unroll
    for (int c = 0; c < 9; ++c) {
        const int kb = c * 3;                  // compile-time (full unroll)

        // ---- stage weight chunk: 3*8KB, coalesced, all 256 threads ----
        {
            const u16x8* gw = reinterpret_cast<const u16x8*>(
                Wt + (size_t)kb * 4096);
            u16x8* lw = reinterpret_cast<u16x8*>(s_w);
#pragma unroll
            for (int i = 0; i < 6; ++i)        // 6*256 = 1536 = 3*512 units
                lw[threadIdx.x + i * 256] = gw[threadIdx.x + i * 256];
        }
        __syncthreads();                       // s_w ready

        // ---- 3 k-steps, A double-buffered by global parity, B from LDS ----
        LOADA(kb + 1);
        LOADB_LDS(0);
        __builtin_amdgcn_sched_barrier(0);
        DOMFMA(kb);

        LOADA(kb + 2);
        LOADB_LDS(1);
        __builtin_amdgcn_sched_barrier(0);
        DOMFMA(kb + 1);

        if (c < 8) LOADA(kb + 3);              // prefetch next chunk's first A
        LOADB_LDS(2);
        __builtin_amdgcn_sched_barrier(0);
        DOMFMA(kb + 2);

        __syncthreads();                       // all waves done with s_w
    }
#undef LOADA
#undef LOADB_LDS
#undef DOMFMA

    // ---- epilogue: bias, store (fp32 or bf16), block stats -> spread atomics
    float* s_red = reinterpret_cast<float*>(s_w);   // 4*128 floats (s_w dead)

#define EPI(STORE_STMT)                                                      \
    _Pragma("unroll")                                                        \
    for (int ct = 0; ct < 4; ++ct) {                                         \
        const int ch = ct * 16 + m;                                          \
        const float bv = bias[ch];                                           \
        float s = 0.f, q = 0.f;                                              \
        _Pragma("unroll")                                                    \
        for (int mt = 0; mt < 2; ++mt) {                                     \
            _Pragma("unroll")                                                \
            for (int r = 0; r < 4; ++r) {                                    \
                const int vox = n0 + lv0 + mt * 16 + quad * 4 + r;           \
                if (vox < N) {                                               \
                    const float v = acc[mt][ct][r] + bv;                     \
                    STORE_STMT;                                              \
                    s += v;                                                  \
                    q += v * v;                                              \
                }                                                            \
            }                                                                \
        }                                                                    \
        s += __shfl_xor(s, 16, 64);                                          \
        s += __shfl_xor(s, 32, 64);                                          \
        q += __shfl_xor(q, 16, 64);                                          \
        q += __shfl_xor(q, 32, 64);                                          \
        if (quad == 0) {                                                     \
            s_red[wv * 128 + ch]      = s;                                   \
            s_red[wv * 128 + 64 + ch] = q;                                   \
        }                                                                    \
    }

    if (fp32out) {
        EPI(((float*)dst)[(size_t)vox * NCH + ch] = v)
    } else {
        EPI(((unsigned short*)dst)[(size_t)vox * NCH + ch] = f2bf(v))
    }
#undef EPI

    __syncthreads();
    if (threadIdx.x < 128) {
        const float v = s_red[threadIdx.x] + s_red[128 + threadIdx.x] +
                        s_red[256 + threadIdx.x] + s_red[384 + threadIdx.x];
        // copy (blockIdx&7), one fp32 per 64B line: ~98 RMWs per address
        atomicAdd(&statOut[(blockIdx.x & 7) * 2048 + threadIdx.x * 16], v);
    }
}

// ---------------------------------------------------------------------------
// BN1 + ReLU, bf16 in -> bf16 out. Folds the 8 stats copies via LDS once
// per block (full-block participation BEFORE any early exit).
// ---------------------------------------------------------------------------
__global__ __launch_bounds__(256)
void bn_relu_bf16_kernel(const unsigned short* __restrict__ x,
                         const float* __restrict__ stats8,
                         const float* __restrict__ gmm, const float* __restrict__ bet,
                         float invN, unsigned short* __restrict__ y, int total8)
{
    __shared__ float sf[128];
    if (threadIdx.x < 128) {
        float a = 0.f;
#pragma unroll
        for (int j = 0; j < 8; ++j)
            a += stats8[j * 2048 + threadIdx.x * 16];
        sf[threadIdx.x] = a;
    }
    __syncthreads();
    const int idx = blockIdx.x * 256 + threadIdx.x;
    if (idx >= total8) return;
    const int c0 = (idx & 7) * 8;
    const u16x8 v = reinterpret_cast<const u16x8*>(x)[idx];
    u16x8 o;
#pragma unroll
    for (int i = 0; i < 8; ++i) {
        const int c = c0 + i;
        const float mu  = sf[c] * invN;
        const float var = sf[64 + c] * invN - mu * mu;
        const float rs  = rsqrtf(var + EPSV);
        const float sc  = gmm[c] * rs;
        const float sh  = bet[c] - mu * sc;
        const float xv  = __uint_as_float(((unsigned)v[i]) << 16);
        o[i] = f2bf(fmaxf(fmaf(xv, sc, sh), 0.f));
    }
    reinterpret_cast<u16x8*>(y)[idx] = o;
}

// ---------------------------------------------------------------------------
// BN2 + residual + ReLU: y2 fp32 + feats -> out fp32. Same 8-copy LDS fold.
// ---------------------------------------------------------------------------
__global__ __launch_bounds__(256)
void bn_res_relu_kernel(const float* __restrict__ x, const float* __restrict__ feats,
                        const float* __restrict__ stats8,
                        const float* __restrict__ gmm, const float* __restrict__ bet,
                        float invN, float* __restrict__ out, int total4)
{
    __shared__ float sf[128];
    if (threadIdx.x < 128) {
        float a = 0.f;
#pragma unroll
        for (int j = 0; j < 8; ++j)
            a += stats8[j * 2048 + threadIdx.x * 16];
        sf[threadIdx.x] = a;
    }
    __syncthreads();
    const int idx = blockIdx.x * blockDim.x + threadIdx.x;
    if (idx >= total4) return;
    const float4 v = reinterpret_cast<const float4*>(x)[idx];
    const float4 f = reinterpret_cast<const float4*>(feats)[idx];
    const int c0 = (idx & 15) * 4;
    float sc[4], sh[4];
#pragma unroll
    for (int i = 0; i < 4; ++i) {
        const int c = c0 + i;
        const float mu  = sf[c] * invN;
        const float var = sf[64 + c] * invN - mu * mu;
        const float rs  = rsqrtf(var + EPSV);
        sc[i] = gmm[c] * rs;
        sh[i] = bet[c] - mu * sc[i];
    }
    float4 o;
    o.x = fmaxf(fmaf(v.x, sc[0], sh[0]) + f.x, 0.f);
    o.y = fmaxf(fmaf(v.y, sc[1], sh[1]) + f.y, 0.f);
    o.z = fmaxf(fmaf(v.z, sc[2], sh[2]) + f.z, 0.f);
    o.w = fmaxf(fmaf(v.w, sc[3], sh[3]) + f.w, 0.f);
    reinterpret_cast<float4*>(out)[idx] = o;
}

extern "C" void kernel_launch(void* const* d_in, const int* in_sizes, int n_in,
                              void* d_out, int out_size, void* d_ws, size_t ws_size,
                              hipStream_t stream)
{
    const float* feats = (const float*)d_in[0];
    const int*   nbr   = (const int*)d_in[1];
    const float* W1    = (const float*)d_in[2];
    const float* b1    = (const float*)d_in[3];
    const float* g1    = (const float*)d_in[4];
    const float* be1   = (const float*)d_in[5];
    const float* W2    = (const float*)d_in[6];
    const float* b2    = (const float*)d_in[7];
    const float* g2    = (const float*)d_in[8];
    const float* be2   = (const float*)d_in[9];
    float* out = (float*)d_out;

    const int N  = in_sizes[0] / NCH;          // 100000
    const int NC = N * NCH;                    // 6,400,000
    const float invN = 1.0f / (float)N;

    // workspace layout with liveness aliasing (peak ~39 MB):
    //   fbf (dead after conv1) + y1 (dead after bn_relu); y2 fp32 overlays
    //   both. Then h1, weights, stats (2 phases x 8 copies x 2048 fp32).
    unsigned short* fbf  = (unsigned short*)d_ws;              // [N*C] bf16
    unsigned short* y1   = fbf + NC;                           // [N*C] bf16
    float*          y2   = (float*)d_ws;                       // [N*C] fp32 (alias)
    unsigned short* h1   = y1 + NC;                            // [N*C] bf16 (bn1 out)
    unsigned short* wt1  = h1 + NC;                            // 110592 bf16
    unsigned short* wt2  = wt1 + KOFF * 4096;                  // 110592 bf16
    float*          stat = (float*)(wt2 + KOFF * 4096);        // 32768 fp32

    const int total8   = NC / 8;                               // 800000
    const int castGrid = (total8 + 255) / 256;                 // 3125
    const int prepGrid = 1 + 108 + castGrid;                   // 3234
    const int convGrid = (N + 127) / 128;                      // 782

    prep_kernel<<<prepGrid, 256, 0, stream>>>(feats, W1, W2, fbf, wt1, wt2,
                                              stat, total8);

    // conv1 -> raw bf16 y1 + stats1 (8-way spread atomics)
    conv_mfma_kernel<<<convGrid, 256, 0, stream>>>(fbf, nbr, wt1, b1, stat,
                                                   (void*)y1, N, 0);

    // BN1 + ReLU: y1 bf16 -> h1 bf16
    bn_relu_bf16_kernel<<<castGrid, 256, 0, stream>>>(y1, stat, g1, be1, invN,
                                                      h1, total8);

    // conv2 -> raw fp32 y2 (overlays dead fbf+y1) + stats2
    conv_mfma_kernel<<<convGrid, 256, 0, stream>>>(h1, nbr, wt2, b2,
                                                   stat + 16384, (void*)y2, N, 1);

    // BN2 + residual + ReLU -> out
    bn_res_relu_kernel<<<(NC / 4 + 255) / 256, 256, 0, stream>>>(
        y2, feats, stat + 16384, g2, be2, invN, out, NC / 4);
}